// Round 23
// baseline (123.170 us; speedup 1.0000x reference)
//
#include <hip/hip_runtime.h>

// SpikingLinearAttention forward — fused chunk-scan kernel, v20.
//  = v19 (R22: 121.0us, best) + final priority-map refinement:
//  staging (write_mat x3: exp+cvtpk+ds_write) elevated to prio 1 — it is
//  BARRIER-BOUND critical-path work (all 8 waves must finish before B2), and
//  was losing issue slots to the co-resident block's prio-1 serial chains.
//  Next-chunk prefetch loads stay at prio 0 (latency-tolerant), as do the
//  walk-finish spin and the output store.
//  Priority map: MFMA clusters=2; serial VALU chains (gate/totals/publish/
//  poll-issue/cumsum/attn) and staging=1; prefetch/spin/store=0.
//  Carried verbatim from v19: fused agg-zeroing k_wsplit (32 blocks), 512
//  blocks (16/batch, 8 chunks each, stride 16, in-register carry), 8 waves,
//  3 af LDS buffers (75KB), 2 barriers/iter, merged K/V GEMM (8 chains),
//  XCD-grouped mapping, 6-term bf16-split MFMA (f32-dot precision), f32
//  gate, in-register in-chunk cumsum (MFMA C/D layout), deterministic
//  decoupled lookback (8B agent atomics).
//  Arbitration-axis wins: 139.3 -> 129.3 -> 126.5 -> 121.0 (R19-R22).

constexpr int cB = 32;
constexpr int cS = 8192;
constexpr int cD = 64;
constexpr int cF = 128;
constexpr int CHUNK = 64;
constexpr int NCH = cS / CHUNK;   // 128 chunks per batch
constexpr int SLOT = 520;         // ushorts per p-plane slot (1040 B)
constexpr int THR = 512;          // 8 waves
constexpr int BPB = 16;           // blocks per batch
constexpr int ITERS = NCH / BPB;  // 8 chunks per block, stride BPB
constexpr float EPS_ = 1e-8f;

typedef __attribute__((ext_vector_type(8))) short bf16x8;  // 8 bf16 (4 VGPRs)
typedef __attribute__((ext_vector_type(4))) float f32x4;   // 4 f32 acc

#define MFMA16(a, b, c) __builtin_amdgcn_mfma_f32_16x16x32_bf16((a), (b), (c), 0, 0, 0)

// ---- bf16 helpers ----------------------------------------------------------
__device__ __forceinline__ unsigned short bf16rn(float x) {
    unsigned u = __float_as_uint(x);
    unsigned r = u + 0x7FFFu + ((u >> 16) & 1u);
    return (unsigned short)(r >> 16);
}
__device__ __forceinline__ float bf16tof(unsigned short h) {
    return __uint_as_float((unsigned)h << 16);
}
__device__ __forceinline__ void split3(float x, unsigned short& a0,
                                       unsigned short& a1, unsigned short& a2) {
    a0 = bf16rn(x);
    float r1 = x - bf16tof(a0);
    a1 = bf16rn(r1);
    float r2 = r1 - bf16tof(a1);
    a2 = bf16rn(r2);
}
// packed RNE bf16 pair (same rounding as bf16rn -> numerically identical)
__device__ __forceinline__ unsigned cvtpk(float lo, float hi) {
    unsigned r;
    asm("v_cvt_pk_bf16_f32 %0, %1, %2" : "=v"(r) : "v"(lo), "v"(hi));
    return r;
}
__device__ __forceinline__ float unpk_lo(unsigned u) {
    return __uint_as_float(u << 16);
}
__device__ __forceinline__ float unpk_hi(unsigned u) {
    return __uint_as_float(u & 0xFFFF0000u);
}

// A-frag: lane l holds A[l&15][(l>>4)*8+j].  B-frag: lane l holds B[(l>>4)*8+j][l&15].
// C/D: lane l, reg r -> row (l>>4)*4+r, col l&15.  [m89-verified, carried]

// ---- K0: split W into B-frag order + zero the agg table --------------------
// 32 blocks x 256 threads. Also zeroes agg (4 MiB): replaces hipMemsetAsync.
__global__ __launch_bounds__(256) void k_wsplit(const float* __restrict__ W,
                                                unsigned short* __restrict__ ws,
                                                unsigned long long* __restrict__ agg) {
    int i = blockIdx.x * 256 + threadIdx.x;
    if (i < cD * cF) {
        int d = i >> 7, f = i & 127;
        unsigned short s0, s1, s2;
        split3(W[i], s0, s1, s2);
        int n = f >> 4, k = d >> 5;
        int lane = (f & 15) | (((d >> 3) & 3) << 4);
        int j = d & 7;
        int base = ((n * 2 + k) * 3) * 512 + lane * 8 + j;
        ws[base]        = s0;
        ws[base + 512]  = s1;
        ws[base + 1024] = s2;
    }
    // zero agg: 32*128*128 = 524288 u64 over 8192 threads = 64 each
    const int NA = cB * NCH * cF;
    for (int a = i; a < NA; a += 32 * 256)
        agg[a] = 0ull;
}

// ---- staging transform: exp + cvt_pk split + swizzled frag-order store -----
// in-slot byte b0 = lane_frag*16 + jj*8 ; stored at b0 ^ (((b0>>8)&3)<<5).
__device__ __forceinline__ void transform_store(float4 a, int idx,
                                                unsigned short* __restrict__ af) {
    int row = idx >> 4, c4 = (idx & 15) * 4;
    float e0 = __expf(a.x), e1 = __expf(a.y), e2 = __expf(a.z), e3 = __expf(a.w);
    uint2 v0;
    v0.x = cvtpk(e0, e1);
    v0.y = cvtpk(e2, e3);
    float r0 = e0 - unpk_lo(v0.x), r1 = e1 - unpk_hi(v0.x);
    float r2 = e2 - unpk_lo(v0.y), r3 = e3 - unpk_hi(v0.y);
    uint2 v1;
    v1.x = cvtpk(r0, r1);
    v1.y = cvtpk(r2, r3);
    float t0 = r0 - unpk_lo(v1.x), t1 = r1 - unpk_hi(v1.x);
    float t2 = r2 - unpk_lo(v1.y), t3 = r3 - unpk_hi(v1.y);
    uint2 v2;
    v2.x = cvtpk(t0, t1);
    v2.y = cvtpk(t2, t3);

    int m = row >> 4, k = c4 >> 5;
    int lane_frag = (row & 15) | (((c4 >> 3) & 3) << 4);
    int jj = (c4 & 7) >> 2;
    int b0 = lane_frag * 16 + jj * 8;
    int byte = b0 ^ (((b0 >> 8) & 3) << 5);
    char* dst = (char*)af + (m * 2 + k) * 3 * (SLOT * 2) + byte;
    *(uint2*)(dst)            = v0;
    *(uint2*)(dst + SLOT * 2) = v1;
    *(uint2*)(dst + SLOT * 4) = v2;
}

__device__ __forceinline__ void load_mat(const float4* __restrict__ src, int t,
                                         float4 ld[2]) {
#pragma unroll
    for (int i = 0; i < 2; ++i) ld[i] = src[t + i * THR];
}
__device__ __forceinline__ void write_mat(const float4 ld[2],
                                          unsigned short* __restrict__ af, int t) {
    transform_store(ld[0], t, af);
    transform_store(ld[1], t + THR, af);
}

__device__ __forceinline__ void read_frag(const unsigned short* __restrict__ af,
                                          int mk, int l, bf16x8* out3) {
    int b0 = l * 16;
    int byte = b0 ^ (((b0 >> 8) & 3) << 5);
    const char* p = (const char*)af + mk * 3 * (SLOT * 2) + byte;
    out3[0] = *(const bf16x8*)(p);
    out3[1] = *(const bf16x8*)(p + SLOT * 2);
    out3[2] = *(const bf16x8*)(p + SLOT * 4);
}

#define GEMM6(acc, A, Wf)            \
    acc = MFMA16(A[0], Wf[0], acc);  \
    acc = MFMA16(A[0], Wf[1], acc);  \
    acc = MFMA16(A[1], Wf[0], acc);  \
    acc = MFMA16(A[1], Wf[1], acc);  \
    acc = MFMA16(A[0], Wf[2], acc);  \
    acc = MFMA16(A[2], Wf[0], acc);

// single-matrix GEMM (used for Q): wave w owns n-tile n=w.
// MFMA cluster at TOP priority (2); caller restores its own level after.
__device__ __forceinline__ void gemm_pass(const unsigned short* __restrict__ af,
                                          const unsigned short* __restrict__ wsplit,
                                          int w, int l, f32x4 acc[4]) {
    __builtin_amdgcn_s_setprio(2);
#pragma unroll
    for (int k = 0; k < 2; ++k) {
        bf16x8 wf[3];
#pragma unroll
        for (int p = 0; p < 3; ++p)
            wf[p] = *(const bf16x8*)(wsplit + (size_t)((((w * 2 + k) * 3 + p) * 512) + l * 8));
#pragma unroll
        for (int m = 0; m < 4; ++m) {
            bf16x8 a[3];
            read_frag(af, m * 2 + k, l, a);
            GEMM6(acc[m], a, wf);
        }
    }
}

// merged K+V GEMM: 8 independent accumulator chains, shared W-frags,
// one ds_read pair per sub-tile feeds two GEMM6 clusters.
__device__ __forceinline__ void gemm_pass2(const unsigned short* __restrict__ afK,
                                           const unsigned short* __restrict__ afV,
                                           const unsigned short* __restrict__ wsplit,
                                           int w, int l,
                                           f32x4 accK[4], f32x4 accV[4]) {
    __builtin_amdgcn_s_setprio(2);
#pragma unroll
    for (int k = 0; k < 2; ++k) {
        bf16x8 wf[3];
#pragma unroll
        for (int p = 0; p < 3; ++p)
            wf[p] = *(const bf16x8*)(wsplit + (size_t)((((w * 2 + k) * 3 + p) * 512) + l * 8));
#pragma unroll
        for (int m = 0; m < 4; ++m) {
            bf16x8 aK[3], aV[3];
            read_frag(afK, m * 2 + k, l, aK);
            read_frag(afV, m * 2 + k, l, aV);
            GEMM6(accK[m], aK, wf);
            GEMM6(accV[m], aV, wf);
        }
    }
}

__device__ __forceinline__ unsigned long long agg_ld(const unsigned long long* p) {
    return __hip_atomic_load(p, __ATOMIC_RELAXED, __HIP_MEMORY_SCOPE_AGENT);
}

// ---- fused kernel ----------------------------------------------------------
__global__ __launch_bounds__(THR, 4) void k_main(const float* __restrict__ Q,
                                                 const float* __restrict__ K,
                                                 const float* __restrict__ V,
                                                 const unsigned short* __restrict__ wsplit,
                                                 float* __restrict__ out,
                                                 unsigned long long* __restrict__ agg)
{
    __shared__ unsigned short afK[24 * SLOT];   // 24960 B each, 74880 total
    __shared__ unsigned short afV[24 * SLOT];
    __shared__ unsigned short afQ[24 * SLOT];

    // XCD-grouped: all 16 blocks of batch b land on XCD b%8 (i = m*32 + b,
    // 32 == 0 mod 8); predecessors (smaller m) have smaller linear id.
    const int i0 = blockIdx.x;
    const int b = i0 & 31, m = i0 >> 5;          // 16 blocks per batch
    const int t = threadIdx.x, w = t >> 6, l = t & 63;
    const int col = l & 15, g = l >> 4;
    const int fidx = w * 16 + col;

    // prologue: load chunk m
    float4 ldK[2], ldV[2], ldQ[2];
    {
        const size_t rb = ((size_t)b * cS + (size_t)m * CHUNK) * cD;
        load_mat((const float4*)(K + rb), t, ldK);
        load_mat((const float4*)(V + rb), t, ldV);
        load_mat((const float4*)(Q + rb), t, ldQ);
    }
    float carK = 0.f, carV = 0.f;   // prefix through previous own chunk (incl)

    for (int j = 0; j < ITERS; ++j) {
        const int c = j * BPB + m;

        // ---- prio 1: stage current chunk (barrier-bound critical path) ----
        __syncthreads();                       // af free (prev iter reads done)
        __builtin_amdgcn_s_setprio(1);
        write_mat(ldK, afK, t);
        write_mat(ldV, afV, t);
        write_mat(ldQ, afQ, t);
        __builtin_amdgcn_s_setprio(0);
        // ---- prio 0: next chunk prefetch (latency-tolerant) ----
        if (j + 1 < ITERS) {
            const size_t rb = ((size_t)b * cS + (size_t)(c + BPB) * CHUNK) * cD;
            load_mat((const float4*)(K + rb), t, ldK);
            load_mat((const float4*)(V + rb), t, ldV);
            load_mat((const float4*)(Q + rb), t, ldQ);
        }
        __syncthreads();                       // af ready

        // ---- prio 2: K and V feature GEMMs (merged, 8 chains) ----
        f32x4 accK[4] = {};
        f32x4 accV[4] = {};
        gemm_pass2(afK, afV, wsplit, w, l, accK, accV);
        __builtin_amdgcn_s_setprio(1);         // stay elevated on serial chain

        // ---- prio 1: gate: accK := k_s, accV := k_s * v_f ----
#pragma unroll
        for (int mm = 0; mm < 4; ++mm)
#pragma unroll
            for (int r = 0; r < 4; ++r) {
                float kf = accK[mm][r];
                float ks = (kf > 0.5f) ? kf : 0.f;
                accK[mm][r] = ks;
                accV[mm][r] = ks * accV[mm][r];
            }

        // ---- prio 1: fast chunk totals (fixed xor tree) + publish ASAP ----
        float ktot = 0.f, kvtot = 0.f;
#pragma unroll
        for (int mm = 0; mm < 4; ++mm)
#pragma unroll
            for (int r = 0; r < 4; ++r) {
                ktot += accK[mm][r];
                kvtot += accV[mm][r];
            }
        ktot += __shfl_xor(ktot, 16);
        ktot += __shfl_xor(ktot, 32);
        kvtot += __shfl_xor(kvtot, 16);
        kvtot += __shfl_xor(kvtot, 32);
        if (g == 0) {
            unsigned long long u = ((unsigned long long)__float_as_uint(kvtot) << 32)
                                 | (unsigned long long)__float_as_uint(ktot + 1.0f);
            __hip_atomic_store(agg + (size_t)(b * NCH + c) * cF + fidx, u,
                               __ATOMIC_RELAXED, __HIP_MEMORY_SCOPE_AGENT);
        }

        // ---- prio 1: issue walk loads (<=4/lane, independent) ----
        const int lastc = (j == 0) ? -1 : (c - BPB);
        const int cc0 = c - 1 - g;
        const unsigned long long* base = agg + (size_t)b * NCH * cF + fidx;
        unsigned long long vv[4];
#pragma unroll
        for (int s2 = 0; s2 < 4; ++s2) {
            int cc = cc0 - 4 * s2;
            vv[s2] = (cc > lastc) ? agg_ld(base + (size_t)cc * cF) : 0ull;
        }

        // ---- prio 1: in-chunk inclusive cumsum (serial VALU chain) ----
        {
            float cK = 0.f, cV = 0.f;
#pragma unroll
            for (int mm = 0; mm < 4; ++mm) {
                f32x4 aK = accK[mm], aV = accV[mm];
                aK[1] += aK[0]; aK[2] += aK[1]; aK[3] += aK[2];
                aV[1] += aV[0]; aV[2] += aV[1]; aV[3] += aV[2];
                float tK = aK[3], tV = aV[3];
                float uK = __shfl_up(tK, 16), uV = __shfl_up(tV, 16);
                if (g >= 1) { tK += uK; tV += uV; }
                float xK = __shfl_up(tK, 32), xV = __shfl_up(tV, 32);
                if (g >= 2) { tK += xK; tV += xV; }
                float eK = tK - aK[3] + cK;
                float eV = tV - aV[3] + cV;
                aK[0] += eK; aK[1] += eK; aK[2] += eK; aK[3] += eK;
                aV[0] += eV; aV[1] += eV; aV[2] += eV; aV[3] += eV;
                accK[mm] = aK; accV[mm] = aV;
                cK += __shfl(tK, 48 + col);
                cV += __shfl(tV, 48 + col);
            }
        }

        // ---- prio 0: finish walk (spin must yield to other block) ----
        __builtin_amdgcn_s_setprio(0);
        {
            float dk = 0.f, dv = 0.f;
#pragma unroll
            for (int s2 = 0; s2 < 4; ++s2) {
                int cc = cc0 - 4 * s2;
                if (cc > lastc) {
                    unsigned long long v0 = vv[s2];
                    while ((unsigned)v0 == 0u) v0 = agg_ld(base + (size_t)cc * cF);
                    dk += __uint_as_float((unsigned)v0) - 1.0f;
                    dv += __uint_as_float((unsigned)(v0 >> 32));
                }
            }
            dk += __shfl_xor(dk, 16);
            dk += __shfl_xor(dk, 32);
            dv += __shfl_xor(dv, 16);
            dv += __shfl_xor(dv, 32);
            carK += dk;            // now = prefix through c-1
            carV += dv;
        }

        // ---- prio 1: attn in place: accV := attn (accK dead after) ----
        __builtin_amdgcn_s_setprio(1);
#pragma unroll
        for (int mm = 0; mm < 4; ++mm)
#pragma unroll
            for (int r = 0; r < 4; ++r) {
                float kc = accK[mm][r] + carK;
                float vc = accV[mm][r] + carV;
                accV[mm][r] = __fdividef(vc + EPS_, kc + EPS_);
            }
        carK += ktot;              // prefix through c (incl own chunk)
        carV += kvtot;

        // ---- prio 2: Q feature GEMM; prio 0: output store ----
        f32x4 accQ[4] = {};
        gemm_pass(afQ, wsplit, w, l, accQ);
        __builtin_amdgcn_s_setprio(0);

        const size_t obase = ((size_t)b * cS + (size_t)c * CHUNK) * cF;
#pragma unroll
        for (int mm = 0; mm < 4; ++mm)
#pragma unroll
            for (int r = 0; r < 4; ++r) {
                int s = mm * 16 + g * 4 + r;
                float qf = accQ[mm][r];
                float qs = (qf > 0.5f) ? qf : 0.f;
                out[obase + (size_t)s * cF + fidx] = qs * accV[mm][r];
            }
    }
}

// ---------------------------------------------------------------------------
extern "C" void kernel_launch(void* const* d_in, const int* in_sizes, int n_in,
                              void* d_out, int out_size, void* d_ws, size_t ws_size,
                              hipStream_t stream) {
    const float* q = (const float*)d_in[0];
    const float* k = (const float*)d_in[1];
    const float* v = (const float*)d_in[2];
    const float* w = (const float*)d_in[3];
    float* out = (float*)d_out;

    unsigned short* wsplit = (unsigned short*)d_ws;                       // 48 KiB
    unsigned long long* agg = (unsigned long long*)((char*)d_ws + 65536); // 4 MiB

    k_wsplit<<<32, 256, 0, stream>>>(w, wsplit, agg);  // also zeroes agg
    k_main<<<cB * BPB, THR, 0, stream>>>(q, k, v, wsplit, out, agg);
}